// Round 3
// baseline (822.086 us; speedup 1.0000x reference)
//
#include <hip/hip_runtime.h>

// MetaTransformer collapse: per layer,
//   G[b]  = Zx[b,:2047]^T Zx[b,:2047]   (256x256, symmetric)   gcol = Zx^T zlab
//   V'_j  = G P_j^T ; M = (1/N) sum_j Q_j V'_j                 mcol = (1/N) Qsum gcol
//   Z[b] += Zx[b] M[b]  (+ label-col GEMV with mcol)
// All MFMA GEMMs in A*B^T form: D[r][c] = sum_k A'[r][k]*B'[c][k], row-major bf16 frags.
// apply fuses next layer's staging (Zxbf ping-pong, Zxt, zlab). 17 dispatches total.

#define NL   4
#define NH   8
#define DD   256
#define NCH  257
#define NTOK 2048
#define NVAL 2047
#define NB   8

typedef short  short8v __attribute__((ext_vector_type(8)));
typedef short  short4v __attribute__((ext_vector_type(4)));
typedef float  f32x4   __attribute__((ext_vector_type(4)));

__device__ __forceinline__ unsigned short f2b(float x) {
  union { float f; unsigned u; } v; v.f = x;
  unsigned u = v.u + 0x7fffu + ((v.u >> 16) & 1u);
  return (unsigned short)(u >> 16);
}
__device__ __forceinline__ float b2f(short s) {
  union { unsigned u; float f; } v; v.u = ((unsigned)(unsigned short)s) << 16;
  return v.f;
}

// ---- MFMA tile helper: 4 waves, 64x64 per wave, K step 32, direct global loads.
__device__ __forceinline__ void mm_tile(const short* A, const short* B,
                                        int lda, int ldb, int ar, int bc, int k0, int k1,
                                        int lane, f32x4 acc[4][4]) {
  #pragma unroll 2
  for (int kk = k0; kk < k1; kk += 32) {
    const int kc = kk + ((lane >> 4) << 3);
    short8v av[4], bv[4];
    #pragma unroll
    for (int f = 0; f < 4; ++f)
      av[f] = *(const short8v*)(A + (size_t)(ar + f * 16 + (lane & 15)) * lda + kc);
    #pragma unroll
    for (int g = 0; g < 4; ++g)
      bv[g] = *(const short8v*)(B + (size_t)(bc + g * 16 + (lane & 15)) * ldb + kc);
    #pragma unroll
    for (int f = 0; f < 4; ++f)
      #pragma unroll
      for (int g = 0; g < 4; ++g)
        acc[f][g] = __builtin_amdgcn_mfma_f32_16x16x32_bf16(av[f], bv[g], acc[f][g], 0, 0, 0);
  }
}

// ---- k_init: flat grid 3136 wgs.
//   [0,2048)     params -> bf16 P,Q
//   [2048,2112)  QsumT[l][t][k] = sum_j Q_j[k][t]
//   [2112,3136)  Zin -> Zxbf0 (natural bf16), Zxt (transposed, m=2047 zeroed), zlab
__global__ __launch_bounds__(256) void k_init(const float* __restrict__ Zin,
                                              const float* __restrict__ ap,
                                              short* __restrict__ Pbf, short* __restrict__ Qbf,
                                              float* __restrict__ QsumT,
                                              short* __restrict__ Zxbf, short* __restrict__ Zxt,
                                              float* __restrict__ zlab) {
  __shared__ float lds[64][65];
  const int bx = blockIdx.x, tid = threadIdx.x;
  if (bx < 2048) {
    int gid = bx * 256 + tid;
    int lj = gid >> 14, rc4 = gid & 16383;
    const f32x4* src = (const f32x4*)ap;
    f32x4 pv = src[(size_t)(lj * 2 + 0) * 16384 + rc4];
    f32x4 qv = src[(size_t)(lj * 2 + 1) * 16384 + rc4];
    short4v p, q;
    #pragma unroll
    for (int i = 0; i < 4; ++i) { p[i] = (short)f2b(pv[i]); q[i] = (short)f2b(qv[i]); }
    ((short4v*)Pbf)[(size_t)lj * 16384 + rc4] = p;
    ((short4v*)Qbf)[(size_t)lj * 16384 + rc4] = q;
    return;
  }
  if (bx < 2112) {
    int qb = bx - 2048;
    int l = qb >> 4, xx = qb & 15;
    int k0 = (xx >> 2) * 64, t0 = (xx & 3) * 64;
    int c = tid & 63, r = tid >> 6;
    #pragma unroll
    for (int i = 0; i < 16; ++i) {
      int k = r + i * 4;
      float s = 0.f;
      #pragma unroll
      for (int j = 0; j < 8; ++j)
        s += ap[(size_t)((l * 8 + j) * 2 + 1) * 65536 + (size_t)(k0 + k) * 256 + (t0 + c)];
      lds[k][c] = s;
    }
    __syncthreads();
    #pragma unroll
    for (int i = 0; i < 16; ++i) {
      int tl = r + i * 4;
      QsumT[(size_t)l * 65536 + (size_t)(t0 + tl) * 256 + (k0 + c)] = lds[c][tl];
    }
    return;
  }
  int tb = bx - 2112;
  int x = tb & 3, y = (tb >> 2) & 31, b = tb >> 7;
  int k0 = x * 64, m0 = y * 64;
  int c = tid & 63, r = tid >> 6;
  #pragma unroll
  for (int i = 0; i < 16; ++i) {
    int mrow = r + i * 4, m = m0 + mrow;
    float v = Zin[((size_t)b * NTOK + m) * NCH + k0 + c];
    lds[mrow][c] = v;
    Zxbf[((size_t)b * NTOK + m) * DD + k0 + c] = (short)f2b(v);
  }
  if (x == 0 && tid < 64) {
    int m = m0 + tid;
    zlab[b * NTOK + m] = (m == NVAL) ? 0.f : Zin[((size_t)b * NTOK + m) * NCH + DD];
  }
  __syncthreads();
  #pragma unroll
  for (int i = 0; i < 16; ++i) {
    int krow = r + i * 4;
    float v = lds[c][krow];
    if (m0 + c == NVAL) v = 0.f;
    Zxt[((size_t)b * DD + k0 + krow) * NTOK + m0 + c] = (short)f2b(v);
  }
}

// ---- k_gram: grid (4, NB). x=0: tile(0,0); x=1: tile(1,1); x=2: tile(0,1)+mirror; x=3: gcol GEMV.
__global__ __launch_bounds__(256) void k_gram(const short* __restrict__ Zxt,
                                              const float* __restrict__ zlab,
                                              short* __restrict__ Gbf, float* __restrict__ gcol) {
  const int b = blockIdx.y, x = blockIdx.x;
  const int tid = threadIdx.x, lane = tid & 63, wid = tid >> 6;
  if (x == 3) {
    __shared__ float zl[NTOK];
    #pragma unroll
    for (int i = 0; i < 8; ++i) zl[tid + i * 256] = zlab[b * NTOK + tid + i * 256];
    __syncthreads();
    const short* row = Zxt + ((size_t)b * DD + tid) * NTOK;
    float s = 0.f;
    for (int m = 0; m < NTOK; m += 8) {
      short8v v = *(const short8v*)(row + m);
      #pragma unroll
      for (int q = 0; q < 8; ++q) s += b2f(v[q]) * zl[m + q];
    }
    gcol[b * DD + tid] = s;
    return;
  }
  const int ar0 = (x == 1) ? 128 : 0;
  const int bc0 = (x == 0) ? 0 : 128;
  const int wr = wid >> 1, wc = wid & 1;
  const int ar = ar0 + wr * 64, bc = bc0 + wc * 64;
  const short* A = Zxt + (size_t)b * DD * NTOK;
  f32x4 acc[4][4];
  #pragma unroll
  for (int f = 0; f < 4; ++f) for (int g = 0; g < 4; ++g) for (int i = 0; i < 4; ++i) acc[f][g][i] = 0.f;
  mm_tile(A, A, NTOK, NTOK, ar, bc, 0, NTOK, lane, acc);
  short* Gb = Gbf + (size_t)b * 65536;
  #pragma unroll
  for (int f = 0; f < 4; ++f) {
    const int rb = ar + f * 16 + ((lane >> 4) << 2);
    #pragma unroll
    for (int g = 0; g < 4; ++g) {
      const int cc = bc + g * 16 + (lane & 15);
      short4v mv;
      #pragma unroll
      for (int i = 0; i < 4; ++i) {
        unsigned short bv = f2b(acc[f][g][i]);
        Gb[(size_t)(rb + i) * 256 + cc] = (short)bv;
        mv[i] = (short)bv;
      }
      if (x == 2) *(short4v*)(Gb + (size_t)cc * 256 + rb) = mv;
    }
  }
}

// ---- k_pmul: Vt[b][j][c][t] = (G P_j^T)[t][c].  A'=G (symmetric), B'=P_j. grid (4,8,NB).
__global__ __launch_bounds__(256) void k_pmul(const short* __restrict__ Gbf, const short* __restrict__ Pbf,
                                              short* __restrict__ Vt, int layer) {
  const int tid = threadIdx.x, lane = tid & 63, wid = tid >> 6;
  const int wr = wid >> 1, wc = wid & 1;
  const int j = blockIdx.y, b = blockIdx.z;
  const int ar = (blockIdx.x >> 1) * 128 + wr * 64;   // t rows
  const int bc = (blockIdx.x & 1) * 128 + wc * 64;    // c rows
  const short* A = Gbf + (size_t)b * 65536;
  const short* B = Pbf + (size_t)(layer * 8 + j) * 65536;
  f32x4 acc[4][4];
  #pragma unroll
  for (int f = 0; f < 4; ++f) for (int g = 0; g < 4; ++g) for (int i = 0; i < 4; ++i) acc[f][g][i] = 0.f;
  mm_tile(A, B, 256, 256, ar, bc, 0, 256, lane, acc);
  short* out = Vt + (size_t)(b * 8 + j) * 65536;
  #pragma unroll
  for (int f = 0; f < 4; ++f) {
    const int t0 = ar + f * 16 + ((lane >> 4) << 2);
    #pragma unroll
    for (int g = 0; g < 4; ++g) {
      const int c = bc + g * 16 + (lane & 15);
      short4v p;
      #pragma unroll
      for (int i = 0; i < 4; ++i) p[i] = (short)f2b(acc[f][g][i]);
      *(short4v*)(out + (size_t)c * 256 + t0) = p;
    }
  }
}

// ---- k_m: grid (5, NB). x<4: M-tile over all 8 heads -> Mt (transposed, invN-scaled).
//          x==4: mcol = invN * QsumT gcol.
__global__ __launch_bounds__(256) void k_m(const short* __restrict__ Qbf, const short* __restrict__ Vt,
                                           const float* __restrict__ QsumT, const float* __restrict__ gcol,
                                           short* __restrict__ Mt, float* __restrict__ mcol, int layer) {
  const float invN = 1.0f / (float)NVAL;
  const int b = blockIdx.y, x = blockIdx.x, tid = threadIdx.x;
  if (x == 4) {
    __shared__ float gs[256];
    gs[tid] = gcol[b * 256 + tid];
    __syncthreads();
    float s = 0.f;
    for (int t = 0; t < 256; ++t) s += QsumT[(size_t)layer * 65536 + (size_t)t * 256 + tid] * gs[t];
    mcol[b * 256 + tid] = s * invN;
    return;
  }
  const int lane = tid & 63, wid = tid >> 6;
  const int wr = wid >> 1, wc = wid & 1;
  const int ar = (x >> 1) * 128 + wr * 64;   // k rows
  const int bc = (x & 1) * 128 + wc * 64;    // c rows
  f32x4 acc[4][4];
  #pragma unroll
  for (int f = 0; f < 4; ++f) for (int g = 0; g < 4; ++g) for (int i = 0; i < 4; ++i) acc[f][g][i] = 0.f;
  for (int j = 0; j < 8; ++j)
    mm_tile(Qbf + (size_t)(layer * 8 + j) * 65536, Vt + (size_t)(b * 8 + j) * 65536,
            256, 256, ar, bc, 0, 256, lane, acc);
  short* out = Mt + (size_t)b * 65536;
  #pragma unroll
  for (int f = 0; f < 4; ++f) {
    const int k0 = ar + f * 16 + ((lane >> 4) << 2);
    #pragma unroll
    for (int g = 0; g < 4; ++g) {
      const int c = bc + g * 16 + (lane & 15);
      short4v p;
      #pragma unroll
      for (int i = 0; i < 4; ++i) p[i] = (short)f2b(acc[f][g][i] * invN);
      *(short4v*)(out + (size_t)c * 256 + k0) = p;
    }
  }
}

// ---- k_apply: Z = Zsrc + Zx M (+ label GEMV); fuses next-layer staging (Zxbf ping-pong, Zxt, zlab).
__global__ __launch_bounds__(256) void k_apply(const float* __restrict__ Zsrc, float* __restrict__ Z,
                                               const short* __restrict__ Zxbf_in, const short* __restrict__ Mt,
                                               const float* __restrict__ mcol,
                                               short* __restrict__ Zxbf_out, short* __restrict__ Zxt_out,
                                               float* __restrict__ zlab_out, int wnext) {
  const int tid = threadIdx.x, lane = tid & 63, wid = tid >> 6;
  const int wr = wid >> 1, wc = wid & 1;
  const int b = blockIdx.z;
  const int ar = blockIdx.y * 128 + wr * 64;          // n rows
  const int bc = blockIdx.x * 128 + wc * 64;          // c rows
  const short* A = Zxbf_in + (size_t)b * NTOK * DD;
  const short* B = Mt + (size_t)b * 65536;
  const bool gemv = (blockIdx.x == 0 && wc == 0);
  f32x4 acc[4][4];
  #pragma unroll
  for (int f = 0; f < 4; ++f) for (int g = 0; g < 4; ++g) for (int i = 0; i < 4; ++i) acc[f][g][i] = 0.f;
  float s[4] = {0.f, 0.f, 0.f, 0.f};
  #pragma unroll 2
  for (int kk = 0; kk < 256; kk += 32) {
    const int kc = kk + ((lane >> 4) << 3);
    short8v av[4], bv[4];
    #pragma unroll
    for (int f = 0; f < 4; ++f)
      av[f] = *(const short8v*)(A + (size_t)(ar + f * 16 + (lane & 15)) * DD + kc);
    #pragma unroll
    for (int g = 0; g < 4; ++g)
      bv[g] = *(const short8v*)(B + (size_t)(bc + g * 16 + (lane & 15)) * 256 + kc);
    if (gemv) {
      const float* mp = mcol + b * 256 + kc;
      f32x4 m0 = *(const f32x4*)mp, m1 = *(const f32x4*)(mp + 4);
      #pragma unroll
      for (int f = 0; f < 4; ++f) {
        #pragma unroll
        for (int q = 0; q < 4; ++q) {
          s[f] += b2f(av[f][q]) * m0[q];
          s[f] += b2f(av[f][4 + q]) * m1[q];
        }
      }
    }
    #pragma unroll
    for (int f = 0; f < 4; ++f)
      #pragma unroll
      for (int g = 0; g < 4; ++g)
        acc[f][g] = __builtin_amdgcn_mfma_f32_16x16x32_bf16(av[f], bv[g], acc[f][g], 0, 0, 0);
  }
  #pragma unroll
  for (int f = 0; f < 4; ++f) {
    const int nb = ar + f * 16 + ((lane >> 4) << 2);
    #pragma unroll
    for (int g = 0; g < 4; ++g) {
      const int c = bc + g * 16 + (lane & 15);
      short4v tz;
      #pragma unroll
      for (int i = 0; i < 4; ++i) {
        size_t idx = ((size_t)b * NTOK + nb + i) * NCH + c;
        float nv = Zsrc[idx] + acc[f][g][i];
        Z[idx] = nv;
        unsigned short bv = f2b(nv);
        if (wnext) Zxbf_out[((size_t)b * NTOK + nb + i) * DD + c] = (short)bv;
        tz[i] = (nb + i == NVAL) ? (short)0 : (short)bv;
      }
      if (wnext) *(short4v*)(Zxt_out + ((size_t)b * DD + c) * NTOK + nb) = tz;
    }
  }
  if (gemv) {
    #pragma unroll
    for (int f = 0; f < 4; ++f) {
      float t = s[f];
      t += __shfl_xor(t, 16);
      t += __shfl_xor(t, 32);
      if ((lane >> 4) == 0) {
        int n = ar + f * 16 + (lane & 15);
        size_t idx = ((size_t)b * NTOK + n) * NCH + DD;
        float nv = Zsrc[idx] + t;
        Z[idx] = nv;
        if (wnext) zlab_out[b * NTOK + n] = (n == NVAL) ? 0.f : nv;
      }
    }
  }
}

// ================= fallback (round-1 fp32 path, used if ws too small) =================
__global__ __launch_bounds__(256) void gram_kernel(const float* __restrict__ Z, float* __restrict__ G) {
  __shared__ float As[32][64];
  __shared__ float Bs[32][65];
  const int c0 = blockIdx.x * 64, k0 = blockIdx.y * 64, b = blockIdx.z;
  const int tid = threadIdx.x, tx = tid & 15, ty = tid >> 4;
  const float* Zb = Z + (size_t)b * NTOK * NCH;
  float acc[4][4] = {};
  for (int m0 = 0; m0 < NVAL; m0 += 32) {
    #pragma unroll
    for (int l = 0; l < 8; ++l) {
      int e = tid + l * 256, mm = e >> 6, kk = e & 63, m = m0 + mm;
      As[mm][kk] = (m < NVAL) ? Zb[(size_t)m * NCH + (k0 + kk)] : 0.f;
    }
    #pragma unroll
    for (int l = 0; l < 8; ++l) {
      int e = tid + l * 256, mm = e >> 6, cc = e & 63, m = m0 + mm, c = c0 + cc;
      Bs[mm][cc] = (m < NVAL && c < NCH) ? Zb[(size_t)m * NCH + c] : 0.f;
    }
    __syncthreads();
    #pragma unroll
    for (int mm = 0; mm < 32; ++mm) {
      float a[4], bb[4];
      #pragma unroll
      for (int i = 0; i < 4; ++i) a[i] = As[mm][ty * 4 + i];
      #pragma unroll
      for (int j = 0; j < 4; ++j) bb[j] = Bs[mm][tx * 4 + j];
      #pragma unroll
      for (int i = 0; i < 4; ++i)
        #pragma unroll
        for (int j = 0; j < 4; ++j) acc[i][j] += a[i] * bb[j];
    }
    __syncthreads();
  }
  float* Gb = G + (size_t)b * DD * NCH;
  #pragma unroll
  for (int i = 0; i < 4; ++i) {
    int k = k0 + ty * 4 + i;
    #pragma unroll
    for (int j = 0; j < 4; ++j) {
      int c = c0 + tx * 4 + j;
      if (c < NCH) Gb[(size_t)k * NCH + c] = acc[i][j];
    }
  }
}
__global__ __launch_bounds__(256) void pmul_kernel(const float* __restrict__ G, const float* __restrict__ allparam,
                                                   float* __restrict__ U, int layer, int j0, int JB) {
  __shared__ float As[64][33];
  __shared__ float Bs[64][33];
  const int c0 = blockIdx.x * 64, k0 = blockIdx.y * 64;
  const int b = blockIdx.z / JB, jj = blockIdx.z % JB, j = j0 + jj;
  const int tid = threadIdx.x, tx = tid & 15, ty = tid >> 4;
  const float* P = allparam + ((size_t)((layer * NH + j) * 2 + 0)) * DD * DD;
  const float* Gb = G + (size_t)b * DD * NCH;
  float acc[4][4] = {};
  for (int t0 = 0; t0 < DD; t0 += 32) {
    #pragma unroll
    for (int l = 0; l < 8; ++l) {
      int e = tid + l * 256, kk = e >> 5, tt = e & 31;
      As[kk][tt] = Gb[(size_t)(k0 + kk) * NCH + (t0 + tt)];
    }
    #pragma unroll
    for (int l = 0; l < 8; ++l) {
      int e = tid + l * 256, cc = e >> 5, tt = e & 31, c = c0 + cc;
      Bs[cc][tt] = (c < DD) ? P[(size_t)c * DD + (t0 + tt)] : 0.f;
    }
    __syncthreads();
    #pragma unroll
    for (int tt = 0; tt < 32; ++tt) {
      float a[4], bb[4];
      #pragma unroll
      for (int i = 0; i < 4; ++i) a[i] = As[ty * 4 + i][tt];
      #pragma unroll
      for (int j2 = 0; j2 < 4; ++j2) bb[j2] = Bs[tx * 4 + j2][tt];
      #pragma unroll
      for (int i = 0; i < 4; ++i)
        #pragma unroll
        for (int j2 = 0; j2 < 4; ++j2) acc[i][j2] += a[i] * bb[j2];
    }
    __syncthreads();
  }
  float* Us = U + ((size_t)(b * JB + jj)) * DD * NCH;
  #pragma unroll
  for (int i = 0; i < 4; ++i) {
    int k = k0 + ty * 4 + i;
    #pragma unroll
    for (int j2 = 0; j2 < 4; ++j2) {
      int c = c0 + tx * 4 + j2;
      if (c < DD)       Us[(size_t)k * NCH + c] = acc[i][j2];
      else if (c == DD) Us[(size_t)k * NCH + c] = Gb[(size_t)k * NCH + DD];
    }
  }
}
__global__ __launch_bounds__(256) void qmul_kernel(const float* __restrict__ U, const float* __restrict__ allparam,
                                                   float* __restrict__ M, int layer, int j0, int jcount, int JB,
                                                   int accumulate) {
  __shared__ float As[64][33];
  __shared__ float Bs[32][65];
  const int c0 = blockIdx.x * 64, k0 = blockIdx.y * 64, b = blockIdx.z;
  const int tid = threadIdx.x, tx = tid & 15, ty = tid >> 4;
  const float invN = 1.0f / (float)NVAL;
  float acc[4][4] = {};
  for (int jj = 0; jj < jcount; ++jj) {
    const float* Q = allparam + ((size_t)((layer * NH + (j0 + jj)) * 2 + 1)) * DD * DD;
    const float* Ub = U + ((size_t)(b * JB + jj)) * DD * NCH;
    for (int t0 = 0; t0 < DD; t0 += 32) {
      #pragma unroll
      for (int l = 0; l < 8; ++l) {
        int e = tid + l * 256, kk = e >> 5, tt = e & 31;
        As[kk][tt] = Q[(size_t)(k0 + kk) * DD + (t0 + tt)];
      }
      #pragma unroll
      for (int l = 0; l < 8; ++l) {
        int e = tid + l * 256, tt = e >> 6, cc = e & 63, c = c0 + cc;
        Bs[tt][cc] = (c < NCH) ? Ub[(size_t)(t0 + tt) * NCH + c] : 0.f;
      }
      __syncthreads();
      #pragma unroll
      for (int tt = 0; tt < 32; ++tt) {
        float a[4], bb[4];
        #pragma unroll
        for (int i = 0; i < 4; ++i) a[i] = As[ty * 4 + i][tt];
        #pragma unroll
        for (int j2 = 0; j2 < 4; ++j2) bb[j2] = Bs[tt][tx * 4 + j2];
        #pragma unroll
        for (int i = 0; i < 4; ++i)
          #pragma unroll
          for (int j2 = 0; j2 < 4; ++j2) acc[i][j2] += a[i] * bb[j2];
      }
      __syncthreads();
    }
  }
  #pragma unroll
  for (int i = 0; i < 4; ++i) {
    int k = k0 + ty * 4 + i;
    #pragma unroll
    for (int j2 = 0; j2 < 4; ++j2) {
      int c = c0 + tx * 4 + j2;
      if (c < NCH) {
        size_t idx = ((size_t)b * DD + k) * NCH + c;
        float v = invN * acc[i][j2];
        M[idx] = accumulate ? (M[idx] + v) : v;
      }
    }
  }
}
__global__ __launch_bounds__(256) void apply_kernel(float* __restrict__ Z, const float* __restrict__ M) {
  __shared__ float Zs[8][256];
  const int b = blockIdx.y, n0 = blockIdx.x * 8;
  float* Zb = Z + (size_t)b * NTOK * NCH;
  const float* Mb = M + (size_t)b * DD * NCH;
  const int tid = threadIdx.x;
  #pragma unroll
  for (int l = 0; l < 8; ++l) {
    int e = tid + l * 256, r = e >> 8, k = e & 255;
    Zs[r][k] = Zb[(size_t)(n0 + r) * NCH + k];
  }
  __syncthreads();
  const int r = tid >> 5, cbase = tid & 31;
  float acc[9] = {};
  #pragma unroll 4
  for (int k = 0; k < 256; ++k) {
    float z = Zs[r][k];
    const float* Mrow = Mb + (size_t)k * NCH;
    #pragma unroll
    for (int ii = 0; ii < 8; ++ii) acc[ii] += z * Mrow[cbase + ii * 32];
    if (cbase == 0) acc[8] += z * Mrow[256];
  }
  #pragma unroll
  for (int ii = 0; ii < 8; ++ii)
    Zb[(size_t)(n0 + r) * NCH + cbase + ii * 32] += acc[ii];
  if (cbase == 0) Zb[(size_t)(n0 + r) * NCH + 256] += acc[8];
}

// =====================================================================================
extern "C" void kernel_launch(void* const* d_in, const int* in_sizes, int n_in,
                              void* d_out, int out_size, void* d_ws, size_t ws_size,
                              hipStream_t stream) {
  const float* Zin      = (const float*)d_in[0];
  const float* allparam = (const float*)d_in[1];
  float* Z = (float*)d_out;

  // ws layout (bytes)
  const size_t o_zx0  = 0;                         // bf16 [8][2048][256]  8,388,608 (ping)
  const size_t o_zx1  = o_zx0  + 8388608;          // bf16                 8,388,608 (pong)
  const size_t o_zxt  = o_zx1  + 8388608;          // bf16 [8][256][2048]  8,388,608
  const size_t o_gbf  = o_zxt  + 8388608;          // bf16 [8][256][256]   1,048,576
  const size_t o_vt   = o_gbf  + 1048576;          // bf16 [8][8][256][256] 8,388,608
  const size_t o_mt   = o_vt   + 8388608;          // bf16 [8][256][256]   1,048,576
  const size_t o_pbf  = o_mt   + 1048576;          // bf16 [4][8][256][256] 4,194,304
  const size_t o_qbf  = o_pbf  + 4194304;          // bf16                 4,194,304
  const size_t o_qsum = o_qbf  + 4194304;          // f32  [4][256][256]   1,048,576
  const size_t o_gcol = o_qsum + 1048576;          // f32  [8][256]        8,192
  const size_t o_mcol = o_gcol + 8192;             // f32  [8][256]        8,192
  const size_t o_zlab = o_mcol + 8192;             // f32  [8][2048]       65,536
  const size_t NEED   = o_zlab + 65536;

  if (ws_size >= NEED) {
    char* wsb = (char*)d_ws;
    short* Zx[2] = { (short*)(wsb + o_zx0), (short*)(wsb + o_zx1) };
    short* Zxt   = (short*)(wsb + o_zxt);
    short* Gbf   = (short*)(wsb + o_gbf);
    short* Vt    = (short*)(wsb + o_vt);
    short* Mt    = (short*)(wsb + o_mt);
    short* Pbf   = (short*)(wsb + o_pbf);
    short* Qbf   = (short*)(wsb + o_qbf);
    float* QsumT = (float*)(wsb + o_qsum);
    float* gcol  = (float*)(wsb + o_gcol);
    float* mcol  = (float*)(wsb + o_mcol);
    float* zlab  = (float*)(wsb + o_zlab);

    k_init<<<dim3(3136), dim3(256), 0, stream>>>(Zin, allparam, Pbf, Qbf, QsumT, Zx[0], Zxt, zlab);

    for (int layer = 0; layer < NL; ++layer) {
      const int cur = layer & 1;
      const int wnext = (layer < NL - 1) ? 1 : 0;
      const float* Zsrc = (layer == 0) ? Zin : Z;
      k_gram<<<dim3(4, NB), dim3(256), 0, stream>>>(Zxt, zlab, Gbf, gcol);
      k_pmul<<<dim3(4, 8, NB), dim3(256), 0, stream>>>(Gbf, Pbf, Vt, layer);
      k_m<<<dim3(5, NB), dim3(256), 0, stream>>>(Qbf, Vt, QsumT, gcol, Mt, mcol, layer);
      k_apply<<<dim3(2, 16, NB), dim3(256), 0, stream>>>(Zsrc, Z, Zx[cur], Mt, mcol,
                                                         Zx[cur ^ 1], Zxt, zlab, wnext);
    }
    return;
  }

  // -------- fallback: round-1 fp32 path --------
  const size_t zbytes = (size_t)NB * NTOK * NCH * sizeof(float);
  hipMemcpyAsync(Z, Zin, zbytes, hipMemcpyDeviceToDevice, stream);
  const size_t Gn = (size_t)NB * DD * NCH;
  float* ws   = (float*)d_ws;
  float* Gbuf = ws;
  float* Mbuf = ws + Gn;
  float* Ubuf = ws + 2 * Gn;
  const int JB = (ws_size >= (size_t)(2 + 8) * Gn * sizeof(float)) ? 8 : 1;
  dim3 blk(256);
  for (int layer = 0; layer < NL; ++layer) {
    gram_kernel<<<dim3(5, 4, NB), blk, 0, stream>>>(Z, Gbuf);
    for (int j0 = 0; j0 < NH; j0 += JB) {
      pmul_kernel<<<dim3(5, 4, NB * JB), blk, 0, stream>>>(Gbuf, allparam, Ubuf, layer, j0, JB);
      qmul_kernel<<<dim3(5, 4, NB), blk, 0, stream>>>(Ubuf, allparam, Mbuf, layer, j0, JB, JB,
                                                      (j0 == 0) ? 0 : 1);
    }
    apply_kernel<<<dim3(NTOK / 8, NB), blk, 0, stream>>>(Z, Mbuf);
  }
}

// Round 4
// 411.204 us; speedup vs baseline: 1.9992x; 1.9992x over previous
//
#include <hip/hip_runtime.h>

// MetaTransformer collapse: per layer,
//   G[b]  = Zx[b,:2047]^T Zx[b,:2047]   (256x256)   gcol = Zx^T zlab
//   V'_j  = G P_j^T ; M = (1/N) sum_j Q_j V'_j      mcol = (1/N) Qsum gcol
//   Z[b] += Zx[b] M[b]  (+ label-col GEMV with mcol)
// All MFMA GEMMs in A*B^T form, row-major bf16 frags. Split-K everywhere for
// parallelism (>=128 wgs per dispatch); fp32 partials reduced by tiny kernels.
// apply fuses next-layer staging (Zxbf ping-pong, Zxt, zlab). 25 dispatches.

#define NL   4
#define NH   8
#define DD   256
#define NCH  257
#define NTOK 2048
#define NVAL 2047
#define NB   8

typedef short  short8v __attribute__((ext_vector_type(8)));
typedef short  short4v __attribute__((ext_vector_type(4)));
typedef float  f32x4   __attribute__((ext_vector_type(4)));

__device__ __forceinline__ unsigned short f2b(float x) {
  union { float f; unsigned u; } v; v.f = x;
  unsigned u = v.u + 0x7fffu + ((v.u >> 16) & 1u);
  return (unsigned short)(u >> 16);
}
__device__ __forceinline__ float b2f(short s) {
  union { unsigned u; float f; } v; v.u = ((unsigned)(unsigned short)s) << 16;
  return v.f;
}

// ---- MFMA tile helper: 4 waves, 64x64 per wave, K step 32, direct global loads.
__device__ __forceinline__ void mm_tile(const short* A, const short* B,
                                        int lda, int ldb, int ar, int bc, int k0, int k1,
                                        int lane, f32x4 acc[4][4]) {
  #pragma unroll 2
  for (int kk = k0; kk < k1; kk += 32) {
    const int kc = kk + ((lane >> 4) << 3);
    short8v av[4], bv[4];
    #pragma unroll
    for (int f = 0; f < 4; ++f)
      av[f] = *(const short8v*)(A + (size_t)(ar + f * 16 + (lane & 15)) * lda + kc);
    #pragma unroll
    for (int g = 0; g < 4; ++g)
      bv[g] = *(const short8v*)(B + (size_t)(bc + g * 16 + (lane & 15)) * ldb + kc);
    #pragma unroll
    for (int f = 0; f < 4; ++f)
      #pragma unroll
      for (int g = 0; g < 4; ++g)
        acc[f][g] = __builtin_amdgcn_mfma_f32_16x16x32_bf16(av[f], bv[g], acc[f][g], 0, 0, 0);
  }
}

// ---- k_init: flat grid 3136 wgs.
//   [0,2048)     params -> bf16 P,Q
//   [2048,2112)  QsumT[l][t][k] = sum_j Q_j[k][t]
//   [2112,3136)  Zin -> Zxbf0 (natural bf16), Zxt (transposed, m=2047 zeroed), zlab
__global__ __launch_bounds__(256) void k_init(const float* __restrict__ Zin,
                                              const float* __restrict__ ap,
                                              short* __restrict__ Pbf, short* __restrict__ Qbf,
                                              float* __restrict__ QsumT,
                                              short* __restrict__ Zxbf, short* __restrict__ Zxt,
                                              float* __restrict__ zlab) {
  __shared__ float lds[64][65];
  const int bx = blockIdx.x, tid = threadIdx.x;
  if (bx < 2048) {
    int gid = bx * 256 + tid;
    int lj = gid >> 14, rc4 = gid & 16383;
    const f32x4* src = (const f32x4*)ap;
    f32x4 pv = src[(size_t)(lj * 2 + 0) * 16384 + rc4];
    f32x4 qv = src[(size_t)(lj * 2 + 1) * 16384 + rc4];
    short4v p, q;
    #pragma unroll
    for (int i = 0; i < 4; ++i) { p[i] = (short)f2b(pv[i]); q[i] = (short)f2b(qv[i]); }
    ((short4v*)Pbf)[(size_t)lj * 16384 + rc4] = p;
    ((short4v*)Qbf)[(size_t)lj * 16384 + rc4] = q;
    return;
  }
  if (bx < 2112) {
    int qb = bx - 2048;
    int l = qb >> 4, xx = qb & 15;
    int k0 = (xx >> 2) * 64, t0 = (xx & 3) * 64;
    int c = tid & 63, r = tid >> 6;
    #pragma unroll
    for (int i = 0; i < 16; ++i) {
      int k = r + i * 4;
      float s = 0.f;
      #pragma unroll
      for (int j = 0; j < 8; ++j)
        s += ap[(size_t)((l * 8 + j) * 2 + 1) * 65536 + (size_t)(k0 + k) * 256 + (t0 + c)];
      lds[k][c] = s;
    }
    __syncthreads();
    #pragma unroll
    for (int i = 0; i < 16; ++i) {
      int tl = r + i * 4;
      QsumT[(size_t)l * 65536 + (size_t)(t0 + tl) * 256 + (k0 + c)] = lds[c][tl];
    }
    return;
  }
  int tb = bx - 2112;
  int x = tb & 3, y = (tb >> 2) & 31, b = tb >> 7;
  int k0 = x * 64, m0 = y * 64;
  int c = tid & 63, r = tid >> 6;
  #pragma unroll
  for (int i = 0; i < 16; ++i) {
    int mrow = r + i * 4, m = m0 + mrow;
    float v = Zin[((size_t)b * NTOK + m) * NCH + k0 + c];
    lds[mrow][c] = v;
    Zxbf[((size_t)b * NTOK + m) * DD + k0 + c] = (short)f2b(v);
  }
  if (x == 0 && tid < 64) {
    int m = m0 + tid;
    zlab[b * NTOK + m] = (m == NVAL) ? 0.f : Zin[((size_t)b * NTOK + m) * NCH + DD];
  }
  __syncthreads();
  #pragma unroll
  for (int i = 0; i < 16; ++i) {
    int krow = r + i * 4;
    float v = lds[c][krow];
    if (m0 + c == NVAL) v = 0.f;
    Zxt[((size_t)b * DD + k0 + krow) * NTOK + m0 + c] = (short)f2b(v);
  }
}

// ---- k_gram: grid (5, 8, NB). x<4: quadrant tile, K-seg -> Gacc[seg][b] fp32.
//              x==4: gcol partial over this seg's 256 m -> gcolacc[seg][b].
__global__ __launch_bounds__(256) void k_gram(const short* __restrict__ Zxt,
                                              const float* __restrict__ zlab,
                                              float* __restrict__ Gacc,
                                              float* __restrict__ gcolacc) {
  const int x = blockIdx.x, seg = blockIdx.y, b = blockIdx.z;
  const int tid = threadIdx.x, lane = tid & 63, wid = tid >> 6;
  if (x == 4) {
    __shared__ float zl[256];
    zl[tid] = zlab[b * NTOK + seg * 256 + tid];
    __syncthreads();
    const short* row = Zxt + ((size_t)b * DD + tid) * NTOK + seg * 256;
    float s = 0.f;
    #pragma unroll 4
    for (int m = 0; m < 256; m += 8) {
      short8v v = *(const short8v*)(row + m);
      #pragma unroll
      for (int q = 0; q < 8; ++q) s += b2f(v[q]) * zl[m + q];
    }
    gcolacc[(seg * 8 + b) * 256 + tid] = s;
    return;
  }
  const int wr = wid >> 1, wc = wid & 1;
  const int ar = (x >> 1) * 128 + wr * 64;
  const int bc = (x & 1) * 128 + wc * 64;
  const short* A = Zxt + (size_t)b * DD * NTOK;
  f32x4 acc[4][4];
  #pragma unroll
  for (int f = 0; f < 4; ++f) for (int g = 0; g < 4; ++g) for (int i = 0; i < 4; ++i) acc[f][g][i] = 0.f;
  mm_tile(A, A, NTOK, NTOK, ar, bc, seg * 256, seg * 256 + 256, lane, acc);
  float* out = Gacc + (size_t)(seg * 8 + b) * 65536;
  #pragma unroll
  for (int f = 0; f < 4; ++f)
    #pragma unroll
    for (int g = 0; g < 4; ++g)
      #pragma unroll
      for (int i = 0; i < 4; ++i)
        out[(size_t)(ar + f * 16 + ((lane >> 4) << 2) + i) * 256 + bc + g * 16 + (lane & 15)] = acc[f][g][i];
}

// ---- k_gconv: grid (264). x<256: Gbf = bf16(sum_seg Gacc). x>=256: gcol = sum_seg gcolacc.
__global__ __launch_bounds__(256) void k_gconv(const float* __restrict__ Gacc,
                                               const float* __restrict__ gcolacc,
                                               short* __restrict__ Gbf, float* __restrict__ gcol) {
  const int bx = blockIdx.x, tid = threadIdx.x;
  if (bx >= 256) {
    const int b = bx - 256;
    float s = 0.f;
    #pragma unroll
    for (int seg = 0; seg < 8; ++seg) s += gcolacc[(seg * 8 + b) * 256 + tid];
    gcol[b * 256 + tid] = s;
    return;
  }
  const int b = bx >> 5, t = bx & 31;
  const int e0 = t * 2048 + tid * 8;
  float a[8];
  #pragma unroll
  for (int i = 0; i < 8; ++i) a[i] = 0.f;
  #pragma unroll
  for (int s = 0; s < 8; ++s) {
    const f32x4* p = (const f32x4*)(Gacc + (size_t)(s * 8 + b) * 65536 + e0);
    f32x4 x = p[0], y = p[1];
    #pragma unroll
    for (int i = 0; i < 4; ++i) { a[i] += x[i]; a[4 + i] += y[i]; }
  }
  short8v o;
  #pragma unroll
  for (int i = 0; i < 8; ++i) o[i] = (short)f2b(a[i]);
  *(short8v*)(Gbf + (size_t)b * 65536 + e0) = o;
}

// ---- k_pmul: Vt[b][j][c][t] = (G P_j^T)[t][c].  A'=G, B'=P_j. grid (4,8,NB).
__global__ __launch_bounds__(256) void k_pmul(const short* __restrict__ Gbf, const short* __restrict__ Pbf,
                                              short* __restrict__ Vt, int layer) {
  const int tid = threadIdx.x, lane = tid & 63, wid = tid >> 6;
  const int wr = wid >> 1, wc = wid & 1;
  const int j = blockIdx.y, b = blockIdx.z;
  const int ar = (blockIdx.x >> 1) * 128 + wr * 64;   // t rows
  const int bc = (blockIdx.x & 1) * 128 + wc * 64;    // c rows
  const short* A = Gbf + (size_t)b * 65536;
  const short* B = Pbf + (size_t)(layer * 8 + j) * 65536;
  f32x4 acc[4][4];
  #pragma unroll
  for (int f = 0; f < 4; ++f) for (int g = 0; g < 4; ++g) for (int i = 0; i < 4; ++i) acc[f][g][i] = 0.f;
  mm_tile(A, B, 256, 256, ar, bc, 0, 256, lane, acc);
  short* out = Vt + (size_t)(b * 8 + j) * 65536;
  #pragma unroll
  for (int f = 0; f < 4; ++f) {
    const int t0 = ar + f * 16 + ((lane >> 4) << 2);
    #pragma unroll
    for (int g = 0; g < 4; ++g) {
      const int c = bc + g * 16 + (lane & 15);
      short4v p;
      #pragma unroll
      for (int i = 0; i < 4; ++i) p[i] = (short)f2b(acc[f][g][i]);
      *(short4v*)(out + (size_t)c * 256 + t0) = p;
    }
  }
}

// ---- k_qmul: Macc[jseg][b] = sum_{j in seg(2)} Q_j V'_j. grid (4,4,NB).
__global__ __launch_bounds__(256) void k_qmul(const short* __restrict__ Qbf, const short* __restrict__ Vt,
                                              float* __restrict__ Macc, int layer) {
  const int tid = threadIdx.x, lane = tid & 63, wid = tid >> 6;
  const int wr = wid >> 1, wc = wid & 1;
  const int jseg = blockIdx.y, b = blockIdx.z;
  const int ar = (blockIdx.x >> 1) * 128 + wr * 64;   // k rows
  const int bc = (blockIdx.x & 1) * 128 + wc * 64;    // c rows
  f32x4 acc[4][4];
  #pragma unroll
  for (int f = 0; f < 4; ++f) for (int g = 0; g < 4; ++g) for (int i = 0; i < 4; ++i) acc[f][g][i] = 0.f;
  for (int jj = jseg * 2; jj < jseg * 2 + 2; ++jj)
    mm_tile(Qbf + (size_t)(layer * 8 + jj) * 65536, Vt + (size_t)(b * 8 + jj) * 65536,
            256, 256, ar, bc, 0, 256, lane, acc);
  float* out = Macc + (size_t)(jseg * 8 + b) * 65536;
  #pragma unroll
  for (int f = 0; f < 4; ++f)
    #pragma unroll
    for (int g = 0; g < 4; ++g)
      #pragma unroll
      for (int i = 0; i < 4; ++i)
        out[(size_t)(ar + f * 16 + ((lane >> 4) << 2) + i) * 256 + bc + g * 16 + (lane & 15)] = acc[f][g][i];
}

// ---- k_mconv: grid (17, NB). x<16: Mt[b][c][k] = bf16(invN * sum_p Macc[p][b][k][c]).
//               x==16: mcol = invN * QsumT gcol.
__global__ __launch_bounds__(256) void k_mconv(const float* __restrict__ Macc, short* __restrict__ Mt,
                                               const float* __restrict__ QsumT, const float* __restrict__ gcol,
                                               float* __restrict__ mcol, int layer) {
  const float invN = 1.0f / (float)NVAL;
  const int b = blockIdx.y, tid = threadIdx.x;
  if (blockIdx.x == 16) {
    __shared__ float gs[256];
    gs[tid] = gcol[b * 256 + tid];
    __syncthreads();
    float s = 0.f;
    for (int t = 0; t < 256; ++t) s += QsumT[(size_t)layer * 65536 + (size_t)t * 256 + tid] * gs[t];
    mcol[b * 256 + tid] = s * invN;
    return;
  }
  __shared__ float lds[64][65];
  const int k0 = (blockIdx.x >> 2) * 64, c0 = (blockIdx.x & 3) * 64;
  const int c = tid & 63, r = tid >> 6;
  #pragma unroll
  for (int i = 0; i < 16; ++i) {
    int k = r + i * 4;
    float s = 0.f;
    #pragma unroll
    for (int p = 0; p < 4; ++p)
      s += Macc[(size_t)(p * 8 + b) * 65536 + (size_t)(k0 + k) * 256 + c0 + c];
    lds[k][c] = s * invN;
  }
  __syncthreads();
  #pragma unroll
  for (int i = 0; i < 16; ++i) {
    int cl = r + i * 4;
    Mt[(size_t)b * 65536 + (size_t)(c0 + cl) * 256 + (k0 + c)] = (short)f2b(lds[c][cl]);
  }
}

// ---- k_apply: Z = Zsrc + Zx M (+ label GEMV); fuses next-layer staging.
__global__ __launch_bounds__(256) void k_apply(const float* __restrict__ Zsrc, float* __restrict__ Z,
                                               const short* __restrict__ Zxbf_in, const short* __restrict__ Mt,
                                               const float* __restrict__ mcol,
                                               short* __restrict__ Zxbf_out, short* __restrict__ Zxt_out,
                                               float* __restrict__ zlab_out, int wnext) {
  const int tid = threadIdx.x, lane = tid & 63, wid = tid >> 6;
  const int wr = wid >> 1, wc = wid & 1;
  const int b = blockIdx.z;
  const int ar = blockIdx.y * 128 + wr * 64;          // n rows
  const int bc = blockIdx.x * 128 + wc * 64;          // c rows
  const short* A = Zxbf_in + (size_t)b * NTOK * DD;
  const short* B = Mt + (size_t)b * 65536;
  const bool gemv = (blockIdx.x == 0 && wc == 0);
  f32x4 acc[4][4];
  #pragma unroll
  for (int f = 0; f < 4; ++f) for (int g = 0; g < 4; ++g) for (int i = 0; i < 4; ++i) acc[f][g][i] = 0.f;
  float s[4] = {0.f, 0.f, 0.f, 0.f};
  #pragma unroll 2
  for (int kk = 0; kk < 256; kk += 32) {
    const int kc = kk + ((lane >> 4) << 3);
    short8v av[4], bv[4];
    #pragma unroll
    for (int f = 0; f < 4; ++f)
      av[f] = *(const short8v*)(A + (size_t)(ar + f * 16 + (lane & 15)) * DD + kc);
    #pragma unroll
    for (int g = 0; g < 4; ++g)
      bv[g] = *(const short8v*)(B + (size_t)(bc + g * 16 + (lane & 15)) * 256 + kc);
    if (gemv) {
      const float* mp = mcol + b * 256 + kc;
      f32x4 m0 = *(const f32x4*)mp, m1 = *(const f32x4*)(mp + 4);
      #pragma unroll
      for (int f = 0; f < 4; ++f) {
        #pragma unroll
        for (int q = 0; q < 4; ++q) {
          s[f] += b2f(av[f][q]) * m0[q];
          s[f] += b2f(av[f][4 + q]) * m1[q];
        }
      }
    }
    #pragma unroll
    for (int f = 0; f < 4; ++f)
      #pragma unroll
      for (int g = 0; g < 4; ++g)
        acc[f][g] = __builtin_amdgcn_mfma_f32_16x16x32_bf16(av[f], bv[g], acc[f][g], 0, 0, 0);
  }
  #pragma unroll
  for (int f = 0; f < 4; ++f) {
    const int nb = ar + f * 16 + ((lane >> 4) << 2);
    #pragma unroll
    for (int g = 0; g < 4; ++g) {
      const int c = bc + g * 16 + (lane & 15);
      short4v tz;
      #pragma unroll
      for (int i = 0; i < 4; ++i) {
        size_t idx = ((size_t)b * NTOK + nb + i) * NCH + c;
        float nv = Zsrc[idx] + acc[f][g][i];
        Z[idx] = nv;
        unsigned short bv = f2b(nv);
        if (wnext) Zxbf_out[((size_t)b * NTOK + nb + i) * DD + c] = (short)bv;
        tz[i] = (nb + i == NVAL) ? (short)0 : (short)bv;
      }
      if (wnext) *(short4v*)(Zxt_out + ((size_t)b * DD + c) * NTOK + nb) = tz;
    }
  }
  if (gemv) {
    #pragma unroll
    for (int f = 0; f < 4; ++f) {
      float t = s[f];
      t += __shfl_xor(t, 16);
      t += __shfl_xor(t, 32);
      if ((lane >> 4) == 0) {
        int n = ar + f * 16 + (lane & 15);
        size_t idx = ((size_t)b * NTOK + n) * NCH + DD;
        float nv = Zsrc[idx] + t;
        Z[idx] = nv;
        if (wnext) zlab_out[b * NTOK + n] = (n == NVAL) ? 0.f : nv;
      }
    }
  }
}

// ================= fallback (round-1 fp32 path, used if ws too small) =================
__global__ __launch_bounds__(256) void gram_kernel(const float* __restrict__ Z, float* __restrict__ G) {
  __shared__ float As[32][64];
  __shared__ float Bs[32][65];
  const int c0 = blockIdx.x * 64, k0 = blockIdx.y * 64, b = blockIdx.z;
  const int tid = threadIdx.x, tx = tid & 15, ty = tid >> 4;
  const float* Zb = Z + (size_t)b * NTOK * NCH;
  float acc[4][4] = {};
  for (int m0 = 0; m0 < NVAL; m0 += 32) {
    #pragma unroll
    for (int l = 0; l < 8; ++l) {
      int e = tid + l * 256, mm = e >> 6, kk = e & 63, m = m0 + mm;
      As[mm][kk] = (m < NVAL) ? Zb[(size_t)m * NCH + (k0 + kk)] : 0.f;
    }
    #pragma unroll
    for (int l = 0; l < 8; ++l) {
      int e = tid + l * 256, mm = e >> 6, cc = e & 63, m = m0 + mm, c = c0 + cc;
      Bs[mm][cc] = (m < NVAL && c < NCH) ? Zb[(size_t)m * NCH + c] : 0.f;
    }
    __syncthreads();
    #pragma unroll
    for (int mm = 0; mm < 32; ++mm) {
      float a[4], bb[4];
      #pragma unroll
      for (int i = 0; i < 4; ++i) a[i] = As[mm][ty * 4 + i];
      #pragma unroll
      for (int j = 0; j < 4; ++j) bb[j] = Bs[mm][tx * 4 + j];
      #pragma unroll
      for (int i = 0; i < 4; ++i)
        #pragma unroll
        for (int j = 0; j < 4; ++j) acc[i][j] += a[i] * bb[j];
    }
    __syncthreads();
  }
  float* Gb = G + (size_t)b * DD * NCH;
  #pragma unroll
  for (int i = 0; i < 4; ++i) {
    int k = k0 + ty * 4 + i;
    #pragma unroll
    for (int j = 0; j < 4; ++j) {
      int c = c0 + tx * 4 + j;
      if (c < NCH) Gb[(size_t)k * NCH + c] = acc[i][j];
    }
  }
}
__global__ __launch_bounds__(256) void pmul_kernel(const float* __restrict__ G, const float* __restrict__ allparam,
                                                   float* __restrict__ U, int layer, int j0, int JB) {
  __shared__ float As[64][33];
  __shared__ float Bs[64][33];
  const int c0 = blockIdx.x * 64, k0 = blockIdx.y * 64;
  const int b = blockIdx.z / JB, jj = blockIdx.z % JB, j = j0 + jj;
  const int tid = threadIdx.x, tx = tid & 15, ty = tid >> 4;
  const float* P = allparam + ((size_t)((layer * NH + j) * 2 + 0)) * DD * DD;
  const float* Gb = G + (size_t)b * DD * NCH;
  float acc[4][4] = {};
  for (int t0 = 0; t0 < DD; t0 += 32) {
    #pragma unroll
    for (int l = 0; l < 8; ++l) {
      int e = tid + l * 256, kk = e >> 5, tt = e & 31;
      As[kk][tt] = Gb[(size_t)(k0 + kk) * NCH + (t0 + tt)];
    }
    #pragma unroll
    for (int l = 0; l < 8; ++l) {
      int e = tid + l * 256, cc = e >> 5, tt = e & 31, c = c0 + cc;
      Bs[cc][tt] = (c < DD) ? P[(size_t)c * DD + (t0 + tt)] : 0.f;
    }
    __syncthreads();
    #pragma unroll
    for (int tt = 0; tt < 32; ++tt) {
      float a[4], bb[4];
      #pragma unroll
      for (int i = 0; i < 4; ++i) a[i] = As[ty * 4 + i][tt];
      #pragma unroll
      for (int j2 = 0; j2 < 4; ++j2) bb[j2] = Bs[tx * 4 + j2][tt];
      #pragma unroll
      for (int i = 0; i < 4; ++i)
        #pragma unroll
        for (int j2 = 0; j2 < 4; ++j2) acc[i][j2] += a[i] * bb[j2];
    }
    __syncthreads();
  }
  float* Us = U + ((size_t)(b * JB + jj)) * DD * NCH;
  #pragma unroll
  for (int i = 0; i < 4; ++i) {
    int k = k0 + ty * 4 + i;
    #pragma unroll
    for (int j2 = 0; j2 < 4; ++j2) {
      int c = c0 + tx * 4 + j2;
      if (c < DD)       Us[(size_t)k * NCH + c] = acc[i][j2];
      else if (c == DD) Us[(size_t)k * NCH + c] = Gb[(size_t)k * NCH + DD];
    }
  }
}
__global__ __launch_bounds__(256) void qmul_kernel(const float* __restrict__ U, const float* __restrict__ allparam,
                                                   float* __restrict__ M, int layer, int j0, int jcount, int JB,
                                                   int accumulate) {
  __shared__ float As[64][33];
  __shared__ float Bs[32][65];
  const int c0 = blockIdx.x * 64, k0 = blockIdx.y * 64, b = blockIdx.z;
  const int tid = threadIdx.x, tx = tid & 15, ty = tid >> 4;
  const float invN = 1.0f / (float)NVAL;
  float acc[4][4] = {};
  for (int jj = 0; jj < jcount; ++jj) {
    const float* Q = allparam + ((size_t)((layer * NH + (j0 + jj)) * 2 + 1)) * DD * DD;
    const float* Ub = U + ((size_t)(b * JB + jj)) * DD * NCH;
    for (int t0 = 0; t0 < DD; t0 += 32) {
      #pragma unroll
      for (int l = 0; l < 8; ++l) {
        int e = tid + l * 256, kk = e >> 5, tt = e & 31;
        As[kk][tt] = Q[(size_t)(k0 + kk) * DD + (t0 + tt)];
      }
      #pragma unroll
      for (int l = 0; l < 8; ++l) {
        int e = tid + l * 256, tt = e >> 6, cc = e & 63, c = c0 + cc;
        Bs[tt][cc] = (c < NCH) ? Ub[(size_t)(t0 + tt) * NCH + c] : 0.f;
      }
      __syncthreads();
      #pragma unroll
      for (int tt = 0; tt < 32; ++tt) {
        float a[4], bb[4];
        #pragma unroll
        for (int i = 0; i < 4; ++i) a[i] = As[ty * 4 + i][tt];
        #pragma unroll
        for (int j2 = 0; j2 < 4; ++j2) bb[j2] = Bs[tt][tx * 4 + j2];
        #pragma unroll
        for (int i = 0; i < 4; ++i)
          #pragma unroll
          for (int j2 = 0; j2 < 4; ++j2) acc[i][j2] += a[i] * bb[j2];
      }
      __syncthreads();
    }
  }
  #pragma unroll
  for (int i = 0; i < 4; ++i) {
    int k = k0 + ty * 4 + i;
    #pragma unroll
    for (int j2 = 0; j2 < 4; ++j2) {
      int c = c0 + tx * 4 + j2;
      if (c < NCH) {
        size_t idx = ((size_t)b * DD + k) * NCH + c;
        float v = invN * acc[i][j2];
        M[idx] = accumulate ? (M[idx] + v) : v;
      }
    }
  }
}
__global__ __launch_bounds__(256) void apply_kernel(float* __restrict__ Z, const float* __restrict__ M) {
  __shared__ float Zs[8][256];
  const int b = blockIdx.y, n0 = blockIdx.x * 8;
  float* Zb = Z + (size_t)b * NTOK * NCH;
  const float* Mb = M + (size_t)b * DD * NCH;
  const int tid = threadIdx.x;
  #pragma unroll
  for (int l = 0; l < 8; ++l) {
    int e = tid + l * 256, r = e >> 8, k = e & 255;
    Zs[r][k] = Zb[(size_t)(n0 + r) * NCH + k];
  }
  __syncthreads();
  const int r = tid >> 5, cbase = tid & 31;
  float acc[9] = {};
  #pragma unroll 4
  for (int k = 0; k < 256; ++k) {
    float z = Zs[r][k];
    const float* Mrow = Mb + (size_t)k * NCH;
    #pragma unroll
    for (int ii = 0; ii < 8; ++ii) acc[ii] += z * Mrow[cbase + ii * 32];
    if (cbase == 0) acc[8] += z * Mrow[256];
  }
  #pragma unroll
  for (int ii = 0; ii < 8; ++ii)
    Zb[(size_t)(n0 + r) * NCH + cbase + ii * 32] += acc[ii];
  if (cbase == 0) Zb[(size_t)(n0 + r) * NCH + 256] += acc[8];
}

// =====================================================================================
extern "C" void kernel_launch(void* const* d_in, const int* in_sizes, int n_in,
                              void* d_out, int out_size, void* d_ws, size_t ws_size,
                              hipStream_t stream) {
  const float* Zin      = (const float*)d_in[0];
  const float* allparam = (const float*)d_in[1];
  float* Z = (float*)d_out;

  // ws layout (bytes)
  const size_t o_zx0  = 0;                         // bf16 [8][2048][256]   8,388,608 (ping)
  const size_t o_zx1  = o_zx0  + 8388608;          // bf16                  8,388,608 (pong)
  const size_t o_zxt  = o_zx1  + 8388608;          // bf16 [8][256][2048]   8,388,608
  const size_t o_gacc = o_zxt  + 8388608;          // f32  [8][8][256][256] 16,777,216 (alias Macc[4][8])
  const size_t o_gbf  = o_gacc + 16777216;         // bf16 [8][256][256]    1,048,576
  const size_t o_vt   = o_gbf  + 1048576;          // bf16 [8][8][256][256] 8,388,608
  const size_t o_mt   = o_vt   + 8388608;          // bf16 [8][256][256]    1,048,576
  const size_t o_pbf  = o_mt   + 1048576;          // bf16 [4][8][256][256] 4,194,304
  const size_t o_qbf  = o_pbf  + 4194304;          // bf16                  4,194,304
  const size_t o_qsum = o_qbf  + 4194304;          // f32  [4][256][256]    1,048,576
  const size_t o_gca  = o_qsum + 1048576;          // f32  [8][8][256]      65,536 (gcolacc)
  const size_t o_gcol = o_gca  + 65536;            // f32  [8][256]         8,192
  const size_t o_mcol = o_gcol + 8192;             // f32  [8][256]         8,192
  const size_t o_zlab = o_mcol + 8192;             // f32  [8][2048]        65,536
  const size_t NEED   = o_zlab + 65536;

  if (ws_size >= NEED) {
    char* wsb = (char*)d_ws;
    short* Zx[2]   = { (short*)(wsb + o_zx0), (short*)(wsb + o_zx1) };
    short* Zxt     = (short*)(wsb + o_zxt);
    float* Gacc    = (float*)(wsb + o_gacc);
    float* Macc    = Gacc;                          // alias (dead after gconv)
    short* Gbf     = (short*)(wsb + o_gbf);
    short* Vt      = (short*)(wsb + o_vt);
    short* Mt      = (short*)(wsb + o_mt);
    short* Pbf     = (short*)(wsb + o_pbf);
    short* Qbf     = (short*)(wsb + o_qbf);
    float* QsumT   = (float*)(wsb + o_qsum);
    float* gcolacc = (float*)(wsb + o_gca);
    float* gcol    = (float*)(wsb + o_gcol);
    float* mcol    = (float*)(wsb + o_mcol);
    float* zlab    = (float*)(wsb + o_zlab);

    k_init<<<dim3(3136), dim3(256), 0, stream>>>(Zin, allparam, Pbf, Qbf, QsumT, Zx[0], Zxt, zlab);

    for (int layer = 0; layer < NL; ++layer) {
      const int cur = layer & 1;
      const int wnext = (layer < NL - 1) ? 1 : 0;
      const float* Zsrc = (layer == 0) ? Zin : Z;
      k_gram<<<dim3(5, 8, NB), dim3(256), 0, stream>>>(Zxt, zlab, Gacc, gcolacc);
      k_gconv<<<dim3(264), dim3(256), 0, stream>>>(Gacc, gcolacc, Gbf, gcol);
      k_pmul<<<dim3(4, 8, NB), dim3(256), 0, stream>>>(Gbf, Pbf, Vt, layer);
      k_qmul<<<dim3(4, 4, NB), dim3(256), 0, stream>>>(Qbf, Vt, Macc, layer);
      k_mconv<<<dim3(17, NB), dim3(256), 0, stream>>>(Macc, Mt, QsumT, gcol, mcol, layer);
      k_apply<<<dim3(2, 16, NB), dim3(256), 0, stream>>>(Zsrc, Z, Zx[cur], Mt, mcol,
                                                         Zx[cur ^ 1], Zxt, zlab, wnext);
    }
    return;
  }

  // -------- fallback: round-1 fp32 path --------
  const size_t zbytes = (size_t)NB * NTOK * NCH * sizeof(float);
  hipMemcpyAsync(Z, Zin, zbytes, hipMemcpyDeviceToDevice, stream);
  const size_t Gn = (size_t)NB * DD * NCH;
  float* ws   = (float*)d_ws;
  float* Gbuf = ws;
  float* Mbuf = ws + Gn;
  float* Ubuf = ws + 2 * Gn;
  const int JB = (ws_size >= (size_t)(2 + 8) * Gn * sizeof(float)) ? 8 : 1;
  dim3 blk(256);
  for (int layer = 0; layer < NL; ++layer) {
    gram_kernel<<<dim3(5, 4, NB), blk, 0, stream>>>(Z, Gbuf);
    for (int j0 = 0; j0 < NH; j0 += JB) {
      pmul_kernel<<<dim3(5, 4, NB * JB), blk, 0, stream>>>(Gbuf, allparam, Ubuf, layer, j0, JB);
      qmul_kernel<<<dim3(5, 4, NB), blk, 0, stream>>>(Ubuf, allparam, Mbuf, layer, j0, JB, JB,
                                                      (j0 == 0) ? 0 : 1);
    }
    apply_kernel<<<dim3(NTOK / 8, NB), blk, 0, stream>>>(Z, Mbuf);
  }
}